// Round 2
// baseline (327.039 us; speedup 1.0000x reference)
//
#include <hip/hip_runtime.h>
#include <hip/hip_bf16.h>

#define D_MODEL 1024
#define N_HEADS 16
#define N_KV    4
#define HD      64
#define SINK    4
#define WIN     256
#define BB      2
#define TT      2048
// M_TOTAL = BB*TT = 4096

typedef __attribute__((ext_vector_type(8))) short  short8;   // 8 bf16 (4 VGPRs)
typedef __attribute__((ext_vector_type(4))) float  f32x4;

static __device__ __forceinline__ unsigned short f2bf(float x) {
    union { __hip_bfloat16 h; unsigned short u; } c;
    c.h = __float2bfloat16(x);
    return c.u;
}
static __device__ __forceinline__ float bf2f(unsigned short u) {
    union { unsigned short u; __hip_bfloat16 h; } c;
    c.u = u;
    return __bfloat162float(c.h);
}

// ---------------------------------------------------------------------------
// X (fp32, [4096][1024]) -> Xhi/Xlo bf16 same layout. 8 elems/thread.
// ---------------------------------------------------------------------------
__global__ __launch_bounds__(256) void convert_x_kernel(
    const float* __restrict__ X, unsigned short* __restrict__ Xhi,
    unsigned short* __restrict__ Xlo, int n)
{
    int i = (blockIdx.x * 256 + threadIdx.x) * 8;
    if (i >= n) return;
    float4 a = *(const float4*)&X[i];
    float4 b = *(const float4*)&X[i + 4];
    float v[8] = {a.x, a.y, a.z, a.w, b.x, b.y, b.z, b.w};
    short8 hi, lo;
#pragma unroll
    for (int j = 0; j < 8; ++j) {
        unsigned short h = f2bf(v[j]);
        hi[j] = (short)h;
        lo[j] = (short)f2bf(v[j] - bf2f(h));
    }
    *(short8*)&Xhi[i] = hi;
    *(short8*)&Xlo[i] = lo;
}

// ---------------------------------------------------------------------------
// W (fp32, [1024][N]) -> Wt hi/lo (bf16, [rowoff+N][1024]) transposed.
// 32x32 LDS tile. grid = (N/32, 32). 256 threads.
// ---------------------------------------------------------------------------
__global__ __launch_bounds__(256) void tconv_kernel(
    const float* __restrict__ src, int N,
    unsigned short* __restrict__ dhi, unsigned short* __restrict__ dlo,
    int rowoff)
{
    __shared__ float lds[32][33];
    const int bn = blockIdx.x, bk = blockIdx.y;
    const int t = threadIdx.x;
    {
        const int kr = t >> 3, nc = (t & 7) * 4;
        float4 v = *(const float4*)&src[(size_t)(bk * 32 + kr) * N + bn * 32 + nc];
        lds[kr][nc + 0] = v.x; lds[kr][nc + 1] = v.y;
        lds[kr][nc + 2] = v.z; lds[kr][nc + 3] = v.w;
    }
    __syncthreads();
    {
        const int nr = t >> 3, kc = (t & 7) * 4;
        unsigned short h4[4], l4[4];
#pragma unroll
        for (int j = 0; j < 4; ++j) {
            float v = lds[kc + j][nr];
            h4[j] = f2bf(v);
            l4[j] = f2bf(v - bf2f(h4[j]));
        }
        size_t o = (size_t)(rowoff + bn * 32 + nr) * 1024 + bk * 32 + kc;
        *(ushort4*)&dhi[o] = make_ushort4(h4[0], h4[1], h4[2], h4[3]);
        *(ushort4*)&dlo[o] = make_ushort4(l4[0], l4[1], l4[2], l4[3]);
    }
}

// ---------------------------------------------------------------------------
// Split-bf16 GEMM: C = (Ah+Al) @ (Bh+Bl)^T-ish, A [4096][1024] row-major K,
// B supplied transposed [Ncols][1024] row-major K. 128x128 tile, BK=32,
// 256 threads = 4 waves (2x2), each wave 64x64 = 4x4 frags of 16x16.
// 3 MFMA passes: Ah*Bh + Ah*Bl + Al*Bh.
// mode 0: route cols into Q/K/V attention layouts. mode 1: plain C.
// ---------------------------------------------------------------------------
__global__ __launch_bounds__(256) void gemm_split_kernel(
    const unsigned short* __restrict__ Ah, const unsigned short* __restrict__ Al,
    const unsigned short* __restrict__ Bh, const unsigned short* __restrict__ Bl,
    float* __restrict__ Qo, float* __restrict__ Ko, float* __restrict__ Vo,
    float* __restrict__ OUT, int mode)
{
    // 4 buffers (Ah,Al,Bh,Bl) of 128 rows x 32 k, padded to 40 shorts/row
    __shared__ __align__(16) unsigned short sm[4][128 * 40];

    const int mt  = blockIdx.x;      // M tile (of 128 rows)
    const int nt  = blockIdx.y;      // N tile (of 128 cols)
    const int tid = threadIdx.x;
    const int lane = tid & 63;
    const int w   = tid >> 6;        // wave 0..3
    const int wr  = w >> 1;          // wave row 0..1
    const int wc  = w & 1;           // wave col 0..1
    const int fr  = lane & 15;       // fragment row/col within 16
    const int kg  = lane >> 4;       // k-group 0..3 (8 bf16 each)

    const int arow0 = mt * 128;
    const int brow0 = nt * 128;

    f32x4 acc[4][4];
#pragma unroll
    for (int i = 0; i < 4; ++i)
#pragma unroll
        for (int j = 0; j < 4; ++j)
            acc[i][j] = (f32x4){0.f, 0.f, 0.f, 0.f};

    for (int k0 = 0; k0 < D_MODEL; k0 += 32) {
        __syncthreads();
        // ---- stage: each thread 2 chunks of 8 bf16 per buffer ----
#pragma unroll
        for (int c = 0; c < 2; ++c) {
            const int ch  = tid + c * 256;     // 0..511
            const int row = ch >> 2;           // 0..127
            const int kc  = ch & 3;            // 0..3
            const int loff = row * 40 + kc * 8;
            const size_t ga = (size_t)(arow0 + row) * 1024 + k0 + kc * 8;
            const size_t gb = (size_t)(brow0 + row) * 1024 + k0 + kc * 8;
            *(short8*)&sm[0][loff] = *(const short8*)&Ah[ga];
            *(short8*)&sm[1][loff] = *(const short8*)&Al[ga];
            *(short8*)&sm[2][loff] = *(const short8*)&Bh[gb];
            *(short8*)&sm[3][loff] = *(const short8*)&Bl[gb];
        }
        __syncthreads();

        // ---- fragments ----
        short8 ah[4], al[4], bh[4], bl[4];
#pragma unroll
        for (int i = 0; i < 4; ++i) {
            const int ao = (wr * 64 + i * 16 + fr) * 40 + kg * 8;
            const int bo = (wc * 64 + i * 16 + fr) * 40 + kg * 8;
            ah[i] = *(const short8*)&sm[0][ao];
            al[i] = *(const short8*)&sm[1][ao];
            bh[i] = *(const short8*)&sm[2][bo];
            bl[i] = *(const short8*)&sm[3][bo];
        }
        // ---- MFMA: 3-pass split ----
#pragma unroll
        for (int mi = 0; mi < 4; ++mi)
#pragma unroll
            for (int ni = 0; ni < 4; ++ni) {
                acc[mi][ni] = __builtin_amdgcn_mfma_f32_16x16x32_bf16(
                    ah[mi], bh[ni], acc[mi][ni], 0, 0, 0);
                acc[mi][ni] = __builtin_amdgcn_mfma_f32_16x16x32_bf16(
                    ah[mi], bl[ni], acc[mi][ni], 0, 0, 0);
                acc[mi][ni] = __builtin_amdgcn_mfma_f32_16x16x32_bf16(
                    al[mi], bh[ni], acc[mi][ni], 0, 0, 0);
            }
    }

    // ---- epilogue: C/D mapping col = lane&15, row = (lane>>4)*4 + reg ----
    const int rowb = mt * 128 + wr * 64 + (lane >> 4) * 4;
    const int colb = nt * 128 + wc * 64 + fr;
#pragma unroll
    for (int mi = 0; mi < 4; ++mi) {
#pragma unroll
        for (int ni = 0; ni < 4; ++ni) {
            const int c = colb + ni * 16;
#pragma unroll
            for (int r = 0; r < 4; ++r) {
                const int m = rowb + mi * 16 + r;
                const float v = acc[mi][ni][r];
                if (mode == 0) {
                    const int b = m >> 11, t = m & 2047;
                    if (c < 1024) {
                        const int h = c >> 6, d = c & 63;
                        Qo[(((size_t)b * N_HEADS + h) * TT + t) * HD + d] = v;
                    } else if (c < 1280) {
                        const int kv = (c - 1024) >> 6, d = c & 63;
                        Ko[(((size_t)b * N_KV + kv) * TT + t) * HD + d] = v;
                    } else {
                        const int kv = (c - 1280) >> 6, d = c & 63;
                        Vo[(((size_t)b * N_KV + kv) * TT + t) * HD + d] = v;
                    }
                } else {
                    OUT[(size_t)m * 1024 + c] = v;
                }
            }
        }
    }
}

// ---------------------------------------------------------------------------
// Sink+window flash attention (fp32). grid = (T/64, H, B); 256 threads;
// 4 threads per query row (16 dims each). Y written as bf16 hi/lo,
// layout (B,T,H,64) == rows of the out-projection GEMM.
// ---------------------------------------------------------------------------
__global__ __launch_bounds__(256) void attn_kernel(
    const float* __restrict__ Q, const float* __restrict__ K,
    const float* __restrict__ V, unsigned short* __restrict__ Yhi,
    unsigned short* __restrict__ Ylo)
{
    __shared__ float Kt[64][68];
    __shared__ float Vt[64][68];
    const int qt  = blockIdx.x;
    const int h   = blockIdx.y;
    const int b   = blockIdx.z;
    const int kv  = h >> 2;
    const int tid = threadIdx.x;
    const int r   = tid >> 2;
    const int c   = tid & 3;
    const int i   = qt * 64 + r;
    const int i0  = qt * 64;

    float qreg[16];
    {
        const float* qp = &Q[(((size_t)b * N_HEADS + h) * TT + i) * HD + c * 16];
        const float sc = 0.125f;
#pragma unroll
        for (int d4 = 0; d4 < 4; ++d4) {
            float4 v = *(const float4*)(qp + d4 * 4);
            qreg[d4*4+0] = v.x * sc; qreg[d4*4+1] = v.y * sc;
            qreg[d4*4+2] = v.z * sc; qreg[d4*4+3] = v.w * sc;
        }
    }

    const int lr = tid >> 2;
    const int lc = (tid & 3) * 16;
    const float* kbase = &K[(((size_t)b * N_KV + kv) * TT) * HD];
    const float* vbase = &V[(((size_t)b * N_KV + kv) * TT) * HD];

    int lo = i0 - (WIN - 1); if (lo < 0) lo = 0;
    const int tstart = lo >> 6;

    float m = -1e30f, l = 0.f;
    float acc[16] = {};

    for (int ti = (tstart > 0 ? tstart - 1 : 0); ti <= qt; ++ti) {
        const int j0 = (tstart > 0 && ti == tstart - 1) ? 0 : ti * 64;
        __syncthreads();
#pragma unroll
        for (int d4 = 0; d4 < 4; ++d4) {
            *(float4*)&Kt[lr][lc + d4*4] = *(const float4*)&kbase[(size_t)(j0 + lr) * HD + lc + d4*4];
            *(float4*)&Vt[lr][lc + d4*4] = *(const float4*)&vbase[(size_t)(j0 + lr) * HD + lc + d4*4];
        }
        __syncthreads();

        for (int cc = 0; cc < 4; ++cc) {
            float s[16];
#pragma unroll
            for (int j = 0; j < 16; ++j) {
                const float* kp = &Kt[cc * 16 + j][c * 16];
                float sum = 0.f;
#pragma unroll
                for (int d4 = 0; d4 < 4; ++d4) {
                    float4 kx = *(const float4*)(kp + d4 * 4);
                    sum = fmaf(qreg[d4*4+0], kx.x, sum);
                    sum = fmaf(qreg[d4*4+1], kx.y, sum);
                    sum = fmaf(qreg[d4*4+2], kx.z, sum);
                    sum = fmaf(qreg[d4*4+3], kx.w, sum);
                }
                s[j] = sum;
            }
            float mnew = m;
#pragma unroll
            for (int j = 0; j < 16; ++j) {
                s[j] += __shfl_xor(s[j], 1);
                s[j] += __shfl_xor(s[j], 2);
                const int jg = j0 + cc * 16 + j;
                const bool valid = (jg <= i) && (jg < SINK || jg >= i - (WIN - 1));
                s[j] = valid ? s[j] : -1e30f;
                mnew = fmaxf(mnew, s[j]);
            }
            if (mnew > -5e29f) {
                const float alpha = __expf(m - mnew);
                l *= alpha;
#pragma unroll
                for (int d = 0; d < 16; ++d) acc[d] *= alpha;
#pragma unroll
                for (int j = 0; j < 16; ++j) {
                    const float p = __expf(s[j] - mnew);
                    l += p;
                    const float* vp = &Vt[cc * 16 + j][c * 16];
#pragma unroll
                    for (int d4 = 0; d4 < 4; ++d4) {
                        float4 vx = *(const float4*)(vp + d4 * 4);
                        acc[d4*4+0] = fmaf(p, vx.x, acc[d4*4+0]);
                        acc[d4*4+1] = fmaf(p, vx.y, acc[d4*4+1]);
                        acc[d4*4+2] = fmaf(p, vx.z, acc[d4*4+2]);
                        acc[d4*4+3] = fmaf(p, vx.w, acc[d4*4+3]);
                    }
                }
                m = mnew;
            }
        }
    }

    const float inv = 1.0f / l;
    const size_t yo = ((size_t)b * TT + i) * 1024 + h * HD + c * 16;
    short8 hi0, lo0, hi1, lo1;
#pragma unroll
    for (int d = 0; d < 8; ++d) {
        float o = acc[d] * inv;
        unsigned short hh = f2bf(o);
        hi0[d] = (short)hh;
        lo0[d] = (short)f2bf(o - bf2f(hh));
    }
#pragma unroll
    for (int d = 0; d < 8; ++d) {
        float o = acc[8 + d] * inv;
        unsigned short hh = f2bf(o);
        hi1[d] = (short)hh;
        lo1[d] = (short)f2bf(o - bf2f(hh));
    }
    *(short8*)&Yhi[yo]     = hi0;
    *(short8*)&Yhi[yo + 8] = hi1;
    *(short8*)&Ylo[yo]     = lo0;
    *(short8*)&Ylo[yo + 8] = lo1;
}

// ---------------------------------------------------------------------------
extern "C" void kernel_launch(void* const* d_in, const int* in_sizes, int n_in,
                              void* d_out, int out_size, void* d_ws, size_t ws_size,
                              hipStream_t stream) {
    const float* X  = (const float*)d_in[0];
    const float* Wq = (const float*)d_in[1];
    const float* Wk = (const float*)d_in[2];
    const float* Wv = (const float*)d_in[3];
    const float* Wo = (const float*)d_in[4];
    float* out = (float*)d_out;

    char* w = (char*)d_ws;
    unsigned short* Xhi    = (unsigned short*)w; w += (size_t)4096 * 1024 * 2;
    unsigned short* Xlo    = (unsigned short*)w; w += (size_t)4096 * 1024 * 2;
    unsigned short* Wqkvhi = (unsigned short*)w; w += (size_t)1536 * 1024 * 2;
    unsigned short* Wqkvlo = (unsigned short*)w; w += (size_t)1536 * 1024 * 2;
    unsigned short* Wohi   = (unsigned short*)w; w += (size_t)1024 * 1024 * 2;
    unsigned short* Wolo   = (unsigned short*)w; w += (size_t)1024 * 1024 * 2;
    float* Q  = (float*)w; w += (size_t)4096 * 1024 * 4;   // (B,H,T,64)
    float* Kp = (float*)w; w += (size_t)1024 * 1024 * 4;   // (B,KV,T,64)
    float* Vp = (float*)w; w += (size_t)1024 * 1024 * 4;
    unsigned short* Yhi = (unsigned short*)w; w += (size_t)4096 * 1024 * 2;
    unsigned short* Ylo = (unsigned short*)w; w += (size_t)4096 * 1024 * 2;
    // total ~69.2 MB of d_ws

    convert_x_kernel<<<2048, 256, 0, stream>>>(X, Xhi, Xlo, 4096 * 1024);
    tconv_kernel<<<dim3(32, 32), 256, 0, stream>>>(Wq, 1024, Wqkvhi, Wqkvlo, 0);
    tconv_kernel<<<dim3(8, 32),  256, 0, stream>>>(Wk, 256,  Wqkvhi, Wqkvlo, 1024);
    tconv_kernel<<<dim3(8, 32),  256, 0, stream>>>(Wv, 256,  Wqkvhi, Wqkvlo, 1280);
    tconv_kernel<<<dim3(32, 32), 256, 0, stream>>>(Wo, 1024, Wohi, Wolo, 0);

    gemm_split_kernel<<<dim3(32, 12), 256, 0, stream>>>(
        Xhi, Xlo, Wqkvhi, Wqkvlo, Q, Kp, Vp, nullptr, 0);

    attn_kernel<<<dim3(TT / 64, N_HEADS, BB), 256, 0, stream>>>(Q, Kp, Vp, Yhi, Ylo);

    gemm_split_kernel<<<dim3(32, 8), 256, 0, stream>>>(
        Yhi, Ylo, Wohi, Wolo, nullptr, nullptr, nullptr, out, 1);
}

// Round 5
// 241.645 us; speedup vs baseline: 1.3534x; 1.3534x over previous
//
#include <hip/hip_runtime.h>
#include <hip/hip_bf16.h>

#define D_MODEL 1024
#define N_HEADS 16
#define N_KV    4
#define HD      64
#define SINK    4
#define WIN     256
#define BB      2
#define TT      2048
// M_TOTAL = BB*TT = 4096

typedef __attribute__((ext_vector_type(8))) short  short8;   // 8 bf16 (4 VGPRs)
typedef __attribute__((ext_vector_type(4))) float  f32x4;

static __device__ __forceinline__ unsigned short f2bf(float x) {
    union { __hip_bfloat16 h; unsigned short u; } c;
    c.h = __float2bfloat16(x);
    return c.u;
}
static __device__ __forceinline__ float bf2f(unsigned short u) {
    union { unsigned short u; __hip_bfloat16 h; } c;
    c.u = u;
    return __bfloat162float(c.h);
}

// ---------------------------------------------------------------------------
// X (fp32, [4096][1024]) -> Xhi/Xlo bf16 same layout. 8 elems/thread.
// ---------------------------------------------------------------------------
__global__ __launch_bounds__(256) void convert_x_kernel(
    const float* __restrict__ X, unsigned short* __restrict__ Xhi,
    unsigned short* __restrict__ Xlo, int n)
{
    int i = (blockIdx.x * 256 + threadIdx.x) * 8;
    if (i >= n) return;
    float4 a = *(const float4*)&X[i];
    float4 b = *(const float4*)&X[i + 4];
    float v[8] = {a.x, a.y, a.z, a.w, b.x, b.y, b.z, b.w};
    short8 hi, lo;
#pragma unroll
    for (int j = 0; j < 8; ++j) {
        unsigned short h = f2bf(v[j]);
        hi[j] = (short)h;
        lo[j] = (short)f2bf(v[j] - bf2f(h));
    }
    *(short8*)&Xhi[i] = hi;
    *(short8*)&Xlo[i] = lo;
}

// ---------------------------------------------------------------------------
// W (fp32, [1024][N]) -> Wt hi/lo (bf16, [rowoff+N][1024]) transposed.
// ---------------------------------------------------------------------------
__global__ __launch_bounds__(256) void tconv_kernel(
    const float* __restrict__ src, int N,
    unsigned short* __restrict__ dhi, unsigned short* __restrict__ dlo,
    int rowoff)
{
    __shared__ float lds[32][33];
    const int bn = blockIdx.x, bk = blockIdx.y;
    const int t = threadIdx.x;
    {
        const int kr = t >> 3, nc = (t & 7) * 4;
        float4 v = *(const float4*)&src[(size_t)(bk * 32 + kr) * N + bn * 32 + nc];
        lds[kr][nc + 0] = v.x; lds[kr][nc + 1] = v.y;
        lds[kr][nc + 2] = v.z; lds[kr][nc + 3] = v.w;
    }
    __syncthreads();
    {
        const int nr = t >> 3, kc = (t & 7) * 4;
        unsigned short h4[4], l4[4];
#pragma unroll
        for (int j = 0; j < 4; ++j) {
            float v = lds[kc + j][nr];
            h4[j] = f2bf(v);
            l4[j] = f2bf(v - bf2f(h4[j]));
        }
        size_t o = (size_t)(rowoff + bn * 32 + nr) * 1024 + bk * 32 + kc;
        *(ushort4*)&dhi[o] = make_ushort4(h4[0], h4[1], h4[2], h4[3]);
        *(ushort4*)&dlo[o] = make_ushort4(l4[0], l4[1], l4[2], l4[3]);
    }
}

// ---------------------------------------------------------------------------
// Split-bf16 GEMM: 128x128 tile, BK=32, 4 waves (validated round 2).
// ---------------------------------------------------------------------------
__global__ __launch_bounds__(256) void gemm_split_kernel(
    const unsigned short* __restrict__ Ah, const unsigned short* __restrict__ Al,
    const unsigned short* __restrict__ Bh, const unsigned short* __restrict__ Bl,
    float* __restrict__ Qo, float* __restrict__ Ko, float* __restrict__ Vo,
    float* __restrict__ OUT, int mode)
{
    __shared__ __align__(16) unsigned short sm[4][128 * 40];

    const int mt  = blockIdx.x;
    const int nt  = blockIdx.y;
    const int tid = threadIdx.x;
    const int lane = tid & 63;
    const int w   = tid >> 6;
    const int wr  = w >> 1;
    const int wc  = w & 1;
    const int fr  = lane & 15;
    const int kg  = lane >> 4;

    const int arow0 = mt * 128;
    const int brow0 = nt * 128;

    f32x4 acc[4][4];
#pragma unroll
    for (int i = 0; i < 4; ++i)
#pragma unroll
        for (int j = 0; j < 4; ++j)
            acc[i][j] = (f32x4){0.f, 0.f, 0.f, 0.f};

    for (int k0 = 0; k0 < D_MODEL; k0 += 32) {
        __syncthreads();
#pragma unroll
        for (int c = 0; c < 2; ++c) {
            const int ch  = tid + c * 256;
            const int row = ch >> 2;
            const int kc  = ch & 3;
            const int loff = row * 40 + kc * 8;
            const size_t ga = (size_t)(arow0 + row) * 1024 + k0 + kc * 8;
            const size_t gb = (size_t)(brow0 + row) * 1024 + k0 + kc * 8;
            *(short8*)&sm[0][loff] = *(const short8*)&Ah[ga];
            *(short8*)&sm[1][loff] = *(const short8*)&Al[ga];
            *(short8*)&sm[2][loff] = *(const short8*)&Bh[gb];
            *(short8*)&sm[3][loff] = *(const short8*)&Bl[gb];
        }
        __syncthreads();

        short8 ah[4], al[4], bh[4], bl[4];
#pragma unroll
        for (int i = 0; i < 4; ++i) {
            const int ao = (wr * 64 + i * 16 + fr) * 40 + kg * 8;
            const int bo = (wc * 64 + i * 16 + fr) * 40 + kg * 8;
            ah[i] = *(const short8*)&sm[0][ao];
            al[i] = *(const short8*)&sm[1][ao];
            bh[i] = *(const short8*)&sm[2][bo];
            bl[i] = *(const short8*)&sm[3][bo];
        }
#pragma unroll
        for (int mi = 0; mi < 4; ++mi)
#pragma unroll
            for (int ni = 0; ni < 4; ++ni) {
                acc[mi][ni] = __builtin_amdgcn_mfma_f32_16x16x32_bf16(
                    ah[mi], bh[ni], acc[mi][ni], 0, 0, 0);
                acc[mi][ni] = __builtin_amdgcn_mfma_f32_16x16x32_bf16(
                    ah[mi], bl[ni], acc[mi][ni], 0, 0, 0);
                acc[mi][ni] = __builtin_amdgcn_mfma_f32_16x16x32_bf16(
                    al[mi], bh[ni], acc[mi][ni], 0, 0, 0);
            }
    }

    const int rowb = mt * 128 + wr * 64 + (lane >> 4) * 4;
    const int colb = nt * 128 + wc * 64 + fr;
#pragma unroll
    for (int mi = 0; mi < 4; ++mi) {
#pragma unroll
        for (int ni = 0; ni < 4; ++ni) {
            const int c = colb + ni * 16;
#pragma unroll
            for (int r = 0; r < 4; ++r) {
                const int m = rowb + mi * 16 + r;
                const float v = acc[mi][ni][r];
                if (mode == 0) {
                    const int b = m >> 11, t = m & 2047;
                    if (c < 1024) {
                        const int h = c >> 6, d = c & 63;
                        Qo[(((size_t)b * N_HEADS + h) * TT + t) * HD + d] = v;
                    } else if (c < 1280) {
                        const int kv = (c - 1024) >> 6, d = c & 63;
                        Ko[(((size_t)b * N_KV + kv) * TT + t) * HD + d] = v;
                    } else {
                        const int kv = (c - 1280) >> 6, d = c & 63;
                        Vo[(((size_t)b * N_KV + kv) * TT + t) * HD + d] = v;
                    }
                } else {
                    OUT[(size_t)m * 1024 + c] = v;
                }
            }
        }
    }
}

// ---------------------------------------------------------------------------
// MFMA flash attention with sink+window mask.
// grid = (T/64, H, B), 256 threads = 4 waves, wave w owns q-rows w*16..w*16+15.
// K/V staged in LDS as split bf16; K [key][dim] (padded 72), V transposed
// [dim][key]. QK^T and PV via 3-pass split mfma_f32_16x16x32_bf16.
// Online softmax in registers (C-layout: col=lane&15, row=(lane>>4)*4+reg).
// Y written coalesced as bf16 hi/lo in layout (B,T,H*64).
// ---------------------------------------------------------------------------
__global__ __launch_bounds__(256) void attn_mfma_kernel(
    const float* __restrict__ Q, const float* __restrict__ K,
    const float* __restrict__ V, unsigned short* __restrict__ Yhi,
    unsigned short* __restrict__ Ylo)
{
    __shared__ __align__(16) unsigned short Kh[64][72];
    __shared__ __align__(16) unsigned short Kl[64][72];
    __shared__ __align__(16) unsigned short Vh[64][72];   // [dim][key]
    __shared__ __align__(16) unsigned short Vl[64][72];   // [dim][key]
    __shared__ __align__(16) unsigned short Ph[64][72];   // [q][key], wave-private rows
    __shared__ __align__(16) unsigned short Pl[64][72];

    const int qt   = blockIdx.x;
    const int h    = blockIdx.y;
    const int b    = blockIdx.z;
    const int kv   = h >> 2;
    const int tid  = threadIdx.x;
    const int lane = tid & 63;
    const int w    = tid >> 6;
    const int fr   = lane & 15;      // fragment row/col
    const int kg   = lane >> 4;      // k-group
    const int i0   = qt * 64;
    const int qrow = w * 16;         // wave's local q-row base

    // ---- Q fragments (hi/lo), pre-scaled by 1/8 (exact) ----
    short8 qh[2], ql[2];
    {
        const float* qp = &Q[(((size_t)b * N_HEADS + h) * TT + i0 + qrow + fr) * HD];
#pragma unroll
        for (int s = 0; s < 2; ++s) {
            const float* p = qp + s * 32 + kg * 8;
            float4 x0 = *(const float4*)p;
            float4 x1 = *(const float4*)(p + 4);
            float v[8] = {x0.x, x0.y, x0.z, x0.w, x1.x, x1.y, x1.z, x1.w};
            short8 h8, l8;
#pragma unroll
            for (int j = 0; j < 8; ++j) {
                float sv = v[j] * 0.125f;
                unsigned short hh = f2bf(sv);
                h8[j] = (short)hh;
                l8[j] = (short)f2bf(sv - bf2f(hh));
            }
            qh[s] = h8; ql[s] = l8;
        }
    }

    const float* kbase = &K[(((size_t)b * N_KV + kv) * TT) * HD];
    const float* vbase = &V[(((size_t)b * N_KV + kv) * TT) * HD];

    float mrow[4], lrow[4];
#pragma unroll
    for (int r = 0; r < 4; ++r) { mrow[r] = -1e30f; lrow[r] = 0.f; }
    f32x4 Oacc[4];
#pragma unroll
    for (int t = 0; t < 4; ++t) Oacc[t] = (f32x4){0.f, 0.f, 0.f, 0.f};

    int lo = i0 - (WIN - 1); if (lo < 0) lo = 0;
    const int tstart = lo >> 6;
    const int tbeg   = (tstart > 0) ? tstart - 1 : 0;

    for (int ti = tbeg; ti <= qt; ++ti) {
        const int j0 = (tstart > 0 && ti == tbeg) ? 0 : ti * 64;

        __syncthreads();
        // ---- stage K (row-major) and V (transposed), split hi/lo ----
        {
            const int key = tid >> 2;
            const int dc  = (tid & 3) * 16;
            const float* kp = &kbase[(size_t)(j0 + key) * HD + dc];
            const float* vp = &vbase[(size_t)(j0 + key) * HD + dc];
            float kvv[16];
            {
                float4 a0 = *(const float4*)(kp + 0);
                float4 a1 = *(const float4*)(kp + 4);
                float4 a2 = *(const float4*)(kp + 8);
                float4 a3 = *(const float4*)(kp + 12);
                kvv[0]=a0.x; kvv[1]=a0.y; kvv[2]=a0.z; kvv[3]=a0.w;
                kvv[4]=a1.x; kvv[5]=a1.y; kvv[6]=a1.z; kvv[7]=a1.w;
                kvv[8]=a2.x; kvv[9]=a2.y; kvv[10]=a2.z; kvv[11]=a2.w;
                kvv[12]=a3.x; kvv[13]=a3.y; kvv[14]=a3.z; kvv[15]=a3.w;
                short8 h0, l0, h1, l1;
#pragma unroll
                for (int j = 0; j < 8; ++j) {
                    unsigned short hh = f2bf(kvv[j]);
                    h0[j] = (short)hh; l0[j] = (short)f2bf(kvv[j] - bf2f(hh));
                }
#pragma unroll
                for (int j = 0; j < 8; ++j) {
                    unsigned short hh = f2bf(kvv[8 + j]);
                    h1[j] = (short)hh; l1[j] = (short)f2bf(kvv[8 + j] - bf2f(hh));
                }
                *(short8*)&Kh[key][dc]     = h0;
                *(short8*)&Kh[key][dc + 8] = h1;
                *(short8*)&Kl[key][dc]     = l0;
                *(short8*)&Kl[key][dc + 8] = l1;
            }
            {
                float4 a0 = *(const float4*)(vp + 0);
                float4 a1 = *(const float4*)(vp + 4);
                float4 a2 = *(const float4*)(vp + 8);
                float4 a3 = *(const float4*)(vp + 12);
                float vv[16];
                vv[0]=a0.x; vv[1]=a0.y; vv[2]=a0.z; vv[3]=a0.w;
                vv[4]=a1.x; vv[5]=a1.y; vv[6]=a1.z; vv[7]=a1.w;
                vv[8]=a2.x; vv[9]=a2.y; vv[10]=a2.z; vv[11]=a2.w;
                vv[12]=a3.x; vv[13]=a3.y; vv[14]=a3.z; vv[15]=a3.w;
#pragma unroll
                for (int j = 0; j < 16; ++j) {
                    unsigned short hh = f2bf(vv[j]);
                    Vh[dc + j][key] = hh;
                    Vl[dc + j][key] = f2bf(vv[j] - bf2f(hh));
                }
            }
        }
        __syncthreads();

        // ---- S = Q K^T (split 3-pass) ----
        f32x4 sacc[4];
#pragma unroll
        for (int kt = 0; kt < 4; ++kt) sacc[kt] = (f32x4){0.f, 0.f, 0.f, 0.f};
#pragma unroll
        for (int kt = 0; kt < 4; ++kt) {
#pragma unroll
            for (int s = 0; s < 2; ++s) {
                short8 kbh = *(const short8*)&Kh[kt * 16 + fr][s * 32 + kg * 8];
                short8 kbl = *(const short8*)&Kl[kt * 16 + fr][s * 32 + kg * 8];
                sacc[kt] = __builtin_amdgcn_mfma_f32_16x16x32_bf16(qh[s], kbh, sacc[kt], 0, 0, 0);
                sacc[kt] = __builtin_amdgcn_mfma_f32_16x16x32_bf16(ql[s], kbh, sacc[kt], 0, 0, 0);
                sacc[kt] = __builtin_amdgcn_mfma_f32_16x16x32_bf16(qh[s], kbl, sacc[kt], 0, 0, 0);
            }
        }

        // ---- mask + online softmax (rows = kg*4 + r, key = j0 + kt*16 + fr) ----
        float tmax[4];
#pragma unroll
        for (int r = 0; r < 4; ++r) tmax[r] = -1e30f;
#pragma unroll
        for (int kt = 0; kt < 4; ++kt) {
            const int jg = j0 + kt * 16 + fr;
#pragma unroll
            for (int r = 0; r < 4; ++r) {
                const int iq = i0 + qrow + kg * 4 + r;
                const bool valid = (jg <= iq) && (jg < SINK || jg >= iq - (WIN - 1));
                float v = valid ? sacc[kt][r] : -1e30f;
                sacc[kt][r] = v;
                tmax[r] = fmaxf(tmax[r], v);
            }
        }
#pragma unroll
        for (int mm = 1; mm <= 8; mm <<= 1)
#pragma unroll
            for (int r = 0; r < 4; ++r)
                tmax[r] = fmaxf(tmax[r], __shfl_xor(tmax[r], mm));

        float alpha[4];
#pragma unroll
        for (int r = 0; r < 4; ++r) {
            const float mn = fmaxf(mrow[r], tmax[r]);
            alpha[r] = __expf(mrow[r] - mn);
            mrow[r] = mn;
            lrow[r] *= alpha[r];
        }
        float psum[4] = {0.f, 0.f, 0.f, 0.f};
#pragma unroll
        for (int kt = 0; kt < 4; ++kt)
#pragma unroll
            for (int r = 0; r < 4; ++r) {
                const float p = __expf(sacc[kt][r] - mrow[r]);
                sacc[kt][r] = p;
                psum[r] += p;
            }
#pragma unroll
        for (int mm = 1; mm <= 8; mm <<= 1)
#pragma unroll
            for (int r = 0; r < 4; ++r)
                psum[r] += __shfl_xor(psum[r], mm);
#pragma unroll
        for (int r = 0; r < 4; ++r) lrow[r] += psum[r];
#pragma unroll
        for (int t = 0; t < 4; ++t)
#pragma unroll
            for (int r = 0; r < 4; ++r)
                Oacc[t][r] *= alpha[r];

        // ---- write P to wave-private LDS rows, reload as A-fragments ----
#pragma unroll
        for (int kt = 0; kt < 4; ++kt)
#pragma unroll
            for (int r = 0; r < 4; ++r) {
                const float p = sacc[kt][r];
                const unsigned short ph = f2bf(p);
                Ph[qrow + kg * 4 + r][kt * 16 + fr] = ph;
                Pl[qrow + kg * 4 + r][kt * 16 + fr] = f2bf(p - bf2f(ph));
            }
        short8 pah[2], pal[2];
#pragma unroll
        for (int ks = 0; ks < 2; ++ks) {
            pah[ks] = *(const short8*)&Ph[qrow + fr][ks * 32 + kg * 8];
            pal[ks] = *(const short8*)&Pl[qrow + fr][ks * 32 + kg * 8];
        }
        // ---- O += P V (split 3-pass) ----
#pragma unroll
        for (int dt = 0; dt < 4; ++dt) {
#pragma unroll
            for (int ks = 0; ks < 2; ++ks) {
                short8 vbh = *(const short8*)&Vh[dt * 16 + fr][ks * 32 + kg * 8];
                short8 vbl = *(const short8*)&Vl[dt * 16 + fr][ks * 32 + kg * 8];
                Oacc[dt] = __builtin_amdgcn_mfma_f32_16x16x32_bf16(pah[ks], vbh, Oacc[dt], 0, 0, 0);
                Oacc[dt] = __builtin_amdgcn_mfma_f32_16x16x32_bf16(pal[ks], vbh, Oacc[dt], 0, 0, 0);
                Oacc[dt] = __builtin_amdgcn_mfma_f32_16x16x32_bf16(pah[ks], vbl, Oacc[dt], 0, 0, 0);
            }
        }
    }

    // ---- normalize, bounce through LDS, coalesced bf16 hi/lo stores ----
    float inv[4];
#pragma unroll
    for (int r = 0; r < 4; ++r) inv[r] = 1.0f / lrow[r];
#pragma unroll
    for (int dt = 0; dt < 4; ++dt)
#pragma unroll
        for (int r = 0; r < 4; ++r) {
            const float o = Oacc[dt][r] * inv[r];
            const unsigned short oh = f2bf(o);
            Ph[qrow + kg * 4 + r][dt * 16 + fr] = oh;
            Pl[qrow + kg * 4 + r][dt * 16 + fr] = f2bf(o - bf2f(oh));
        }
    {
        const int row = qrow + (lane >> 2);
        const int d0  = (lane & 3) * 16;
        const size_t yo = ((size_t)b * TT + i0 + row) * 1024 + h * 64 + d0;
        *(short8*)&Yhi[yo]     = *(const short8*)&Ph[row][d0];
        *(short8*)&Yhi[yo + 8] = *(const short8*)&Ph[row][d0 + 8];
        *(short8*)&Ylo[yo]     = *(const short8*)&Pl[row][d0];
        *(short8*)&Ylo[yo + 8] = *(const short8*)&Pl[row][d0 + 8];
    }
}

// ---------------------------------------------------------------------------
extern "C" void kernel_launch(void* const* d_in, const int* in_sizes, int n_in,
                              void* d_out, int out_size, void* d_ws, size_t ws_size,
                              hipStream_t stream) {
    const float* X  = (const float*)d_in[0];
    const float* Wq = (const float*)d_in[1];
    const float* Wk = (const float*)d_in[2];
    const float* Wv = (const float*)d_in[3];
    const float* Wo = (const float*)d_in[4];
    float* out = (float*)d_out;

    char* w = (char*)d_ws;
    unsigned short* Xhi    = (unsigned short*)w; w += (size_t)4096 * 1024 * 2;
    unsigned short* Xlo    = (unsigned short*)w; w += (size_t)4096 * 1024 * 2;
    unsigned short* Wqkvhi = (unsigned short*)w; w += (size_t)1536 * 1024 * 2;
    unsigned short* Wqkvlo = (unsigned short*)w; w += (size_t)1536 * 1024 * 2;
    unsigned short* Wohi   = (unsigned short*)w; w += (size_t)1024 * 1024 * 2;
    unsigned short* Wolo   = (unsigned short*)w; w += (size_t)1024 * 1024 * 2;
    float* Q  = (float*)w; w += (size_t)4096 * 1024 * 4;   // (B,H,T,64)
    float* Kp = (float*)w; w += (size_t)1024 * 1024 * 4;   // (B,KV,T,64)
    float* Vp = (float*)w; w += (size_t)1024 * 1024 * 4;
    unsigned short* Yhi = (unsigned short*)w; w += (size_t)4096 * 1024 * 2;
    unsigned short* Ylo = (unsigned short*)w; w += (size_t)4096 * 1024 * 2;

    convert_x_kernel<<<2048, 256, 0, stream>>>(X, Xhi, Xlo, 4096 * 1024);
    tconv_kernel<<<dim3(32, 32), 256, 0, stream>>>(Wq, 1024, Wqkvhi, Wqkvlo, 0);
    tconv_kernel<<<dim3(8, 32),  256, 0, stream>>>(Wk, 256,  Wqkvhi, Wqkvlo, 1024);
    tconv_kernel<<<dim3(8, 32),  256, 0, stream>>>(Wv, 256,  Wqkvhi, Wqkvlo, 1280);
    tconv_kernel<<<dim3(32, 32), 256, 0, stream>>>(Wo, 1024, Wohi, Wolo, 0);

    gemm_split_kernel<<<dim3(32, 12), 256, 0, stream>>>(
        Xhi, Xlo, Wqkvhi, Wqkvlo, Q, Kp, Vp, nullptr, 0);

    attn_mfma_kernel<<<dim3(TT / 64, N_HEADS, BB), 256, 0, stream>>>(Q, Kp, Vp, Yhi, Ylo);

    gemm_split_kernel<<<dim3(32, 8), 256, 0, stream>>>(
        Yhi, Ylo, Wohi, Wolo, nullptr, nullptr, nullptr, out, 1);
}